// Round 8
// baseline (913.156 us; speedup 1.0000x reference)
//
#include <hip/hip_runtime.h>

#define N_NODES 50000
#define N_EDGES 400000
#define DH 128
#define N_GRAPHS 256

#define SCAN_CHUNK 512
#define N_CHUNKS ((N_NODES + SCAN_CHUNK - 1) / SCAN_CHUNK)   // 98
#define ATTN_BLOCKS ((N_NODES + 15) / 16)                    // 3125
#define POOL_CHUNKS ((N_NODES + 63) / 64)                    // 782
#define NB_GEMM ((N_NODES + 63) / 64)                        // 782
#define PSLOTS 16

typedef __bf16 bf16x8 __attribute__((ext_vector_type(8)));
typedef float f32x4 __attribute__((ext_vector_type(4)));
typedef _Float16 f16x2 __attribute__((ext_vector_type(2)));
typedef _Float16 f16x8 __attribute__((ext_vector_type(8)));

#define DEV __device__ __forceinline__

#if defined(__has_builtin)
#if __has_builtin(__builtin_amdgcn_fdot2)
#define HAS_FDOT2 1
#endif
#endif

DEV float fdot2acc(f16x2 a, f16x2 b, float c) {
#ifdef HAS_FDOT2
  return __builtin_amdgcn_fdot2(a, b, c, false);
#else
  return (float)a.x * (float)b.x + (float)a.y * (float)b.y + c;
#endif
}

DEV unsigned short f2bf(float f) {
  union { float f; unsigned int i; } v; v.f = f;
  unsigned int x = v.i;
  unsigned int r = (x + 0x7fffu + ((x >> 16) & 1u)) >> 16;
  return (unsigned short)r;
}

struct WPtrs { const float* w[12]; };

// ---- setup: weight repack + zero deg/ctrl/ppool (replaces repack + memset) --
__global__ __launch_bounds__(256) void repack_zero(
    WPtrs wp, unsigned short* __restrict__ WB,
    int* __restrict__ deg, int* __restrict__ ctrl, float* __restrict__ ppool,
    int N)
{
  const int T = 768 * 256;
  int gtid = blockIdx.x * 256 + threadIdx.x;
  for (int m = gtid; m < 12 * 16384; m += T) {
    int mat = m >> 14;
    int mm = m & 16383;
    int j = mm & 7;
    int lane = (mm >> 3) & 63;
    int ct = (mm >> 9) & 7;
    int kk = mm >> 12;
    int i = kk * 32 + (lane >> 4) * 8 + j;
    int o = ct * 16 + (lane & 15);
    WB[m] = f2bf(wp.w[mat][i * 128 + o]);
  }
  for (int i = gtid; i < N; i += T) deg[i] = 0;
  if (gtid < 64) ctrl[gtid] = 0;
  for (int i = gtid; i < N_GRAPHS * PSLOTS * 128; i += T) ppool[i] = 0.f;
}

// ---------------- CSR build (split kernels: full occupancy per phase) --------
__global__ void deg_count(const int* __restrict__ ei, int* __restrict__ deg, int E) {
  int e = blockIdx.x * 256 + threadIdx.x;
  if (e < E) atomicAdd(&deg[ei[E + e]], 1);
}

__global__ __launch_bounds__(256) void scan_sum(const int* __restrict__ deg,
                                                int* __restrict__ partials, int N) {
  __shared__ int red[256];
  int b = blockIdx.x, t = threadIdx.x;
  int base = b * SCAN_CHUNK + t * 2;
  int s = 0;
  if (base + 1 < N) { int2 v = *reinterpret_cast<const int2*>(deg + base); s = v.x + v.y; }
  else if (base < N) s = deg[base];
  red[t] = s;
  __syncthreads();
  for (int off = 128; off; off >>= 1) {
    if (t < off) red[t] += red[t + off];
    __syncthreads();
  }
  if (t == 0) partials[b] = red[0];
}

__global__ __launch_bounds__(256) void scan_apply(const int* __restrict__ deg,
                                                  const int* __restrict__ partials,
                                                  int* __restrict__ rowptr,
                                                  int* __restrict__ cursor, int N, int E) {
  __shared__ int s[256];
  __shared__ int prefSh;
  int b = blockIdx.x, t = threadIdx.x;

  s[t] = (t < b) ? partials[t] : 0;    // b <= 97 < 256
  __syncthreads();
  for (int off = 128; off; off >>= 1) {
    if (t < off) s[t] += s[t + off];
    __syncthreads();
  }
  if (t == 0) prefSh = s[0];
  __syncthreads();
  int pref = prefSh;
  __syncthreads();

  int base = b * SCAN_CHUNK + t * 2;
  int d0 = 0, d1 = 0;
  if (base + 1 < N) { int2 v = *reinterpret_cast<const int2*>(deg + base); d0 = v.x; d1 = v.y; }
  else if (base < N) d0 = deg[base];
  int local = d0 + d1;
  s[t] = local;
  __syncthreads();
  for (int off = 1; off < 256; off <<= 1) {
    int o = (t >= off) ? s[t - off] : 0;
    __syncthreads();
    s[t] += o;
    __syncthreads();
  }
  int offp = pref + s[t] - local;
  if (base < N)     { rowptr[base] = offp;          cursor[base] = offp; }
  if (base + 1 < N) { rowptr[base + 1] = offp + d0; cursor[base + 1] = offp + d0; }
  if (b == 0 && t == 0) rowptr[N] = E;
}

__global__ void csr_scatter(const int* __restrict__ ei, int* __restrict__ cursor,
                            int* __restrict__ adj, int E) {
  int e = blockIdx.x * 256 + threadIdx.x;
  if (e < E) {
    int dst = ei[E + e];
    int pos = atomicAdd(&cursor[dst], 1);
    adj[pos] = ei[e];
  }
}

// Canonical stable ascending rank-sort of one batch of 16 rows (16 lanes/row).
// Identical result to insertion sort; called from gemm L0's extra blocks.
DEV void adj_sort_body(const int* __restrict__ rowptr, int* __restrict__ adj,
                       int nodeBase, int N) {
  __shared__ int sbuf[16 * 32];
  int t = threadIdx.x;
  int g = t >> 4, l = t & 15;
  int n = nodeBase + g;
  bool valid = n < N;
  int p0 = 0, d = 0;
  if (valid) { p0 = rowptr[n]; d = rowptr[n + 1] - p0; }
  if (__builtin_expect(d > 32, 0)) {
    if (l == 0) {                      // rare fallback: serial insertion sort
      for (int i = p0 + 1; i < p0 + d; ++i) {
        int v = adj[i]; int j = i - 1;
        while (j >= p0 && adj[j] > v) { adj[j + 1] = adj[j]; --j; }
        adj[j + 1] = v;
      }
    }
    d = 0;
  }
  int a0 = (l < d) ? adj[p0 + l] : 0x7fffffff;
  int a1 = (16 + l < d) ? adj[p0 + 16 + l] : 0x7fffffff;
  int r0 = 0, r1 = 0;
#pragma unroll
  for (int i = 0; i < 16; ++i) {
    int v0 = __shfl(a0, i, 16);
    int v1 = __shfl(a1, i, 16);
    r0 += (v0 < a0) || (v0 == a0 && i < l);
    r0 += (v1 < a0);
    r1 += (v0 <= a1);
    r1 += (v1 < a1) || (v1 == a1 && i < l);
  }
  if (l < d)      sbuf[g * 32 + r0] = a0;
  if (16 + l < d) sbuf[g * 32 + r1] = a1;
  __syncthreads();
  if (l < d)      adj[p0 + l]      = sbuf[g * 32 + l];
  if (16 + l < d) adj[p0 + 16 + l] = sbuf[g * 32 + 16 + l];
}

// BN reduce folded into the CONSUMER kernel's prologue. Blocks ticket at
// START; the last-64-to-arrive ranks perform reduceA (slot = rank-(nb-64),
// fixed row set per slot -> values bit-identical to the old bn_fused
// regardless of physical block), last of those does reduceB + sets flag.
// Deadlock-free: reducers have already ticketed (they are running), and the
// caller guarantees all nb blocks are co-resident. Fences: 64/layer at block
// start only — NOT the R5 pattern (3125 fences amid gather loops).
DEV void bn_prologue(const float* __restrict__ Pbuf, float* __restrict__ bnpart,
                     const float* __restrict__ gamma, const float* __restrict__ beta,
                     float* __restrict__ scale, float* __restrict__ shift,
                     int* __restrict__ sync, int nb, int N) {
  __shared__ int rankSh;
  __shared__ int lastSh;
  __shared__ float red[256];
  int t = threadIdx.x;
  if (t == 0) rankSh = atomicAdd(&sync[0], 1);
  __syncthreads();
  int rank = rankSh;
  if (rank >= nb - 64 && rank < nb) {          // rank<nb guards stale replays
    int slot = rank - (nb - 64);               // 0..63
    float s0 = 0.f, s1 = 0.f, s2 = 0.f, s3 = 0.f;
    int r = slot;
    for (; r + 192 < ATTN_BLOCKS; r += 256) {
      s0 += Pbuf[(size_t)(r      ) * 256 + t];
      s1 += Pbuf[(size_t)(r +  64) * 256 + t];
      s2 += Pbuf[(size_t)(r + 128) * 256 + t];
      s3 += Pbuf[(size_t)(r + 192) * 256 + t];
    }
    for (; r < ATTN_BLOCKS; r += 64) s0 += Pbuf[(size_t)r * 256 + t];
    bnpart[slot * 256 + t] = s0 + s1 + s2 + s3;
    __threadfence();
    if (t == 0) lastSh = (atomicAdd(&sync[1], 1) == 63);
    __syncthreads();
    if (lastSh) {
      __threadfence();
      float v0 = 0.f, v1 = 0.f, v2 = 0.f, v3 = 0.f;
#pragma unroll
      for (int q = 0; q < 64; q += 4) {
        v0 += bnpart[(q + 0) * 256 + t];
        v1 += bnpart[(q + 1) * 256 + t];
        v2 += bnpart[(q + 2) * 256 + t];
        v3 += bnpart[(q + 3) * 256 + t];
      }
      red[t] = v0 + v1 + v2 + v3;
      __syncthreads();
      if (t < 128) {
        float mean = red[t] / (float)N;
        float var = red[t + 128] / (float)N - mean * mean;
        var = fmaxf(var, 0.f);
        float sc = gamma[t] * rsqrtf(var + 1e-5f);
        scale[t] = sc;
        shift[t] = beta[t] - mean * sc;
      }
      __syncthreads();
      __threadfence();                          // release scale/shift
      if (t == 0)
        __hip_atomic_store(&sync[2], 1, __ATOMIC_RELEASE, __HIP_MEMORY_SCOPE_AGENT);
    }
  }
  if (t == 0) {
    while (__hip_atomic_load(&sync[2], __ATOMIC_ACQUIRE,
                             __HIP_MEMORY_SCOPE_AGENT) == 0) {}
  }
  __syncthreads();
}

// ---------------- fused 4-projection GEMM: {Q,K,V,H} = BN(X) @ W_p + b_p -----
// __launch_bounds__(256,4): guarantees 4 blocks/CU (1024 resident >= 782) so
// the bn_prologue spin cannot deadlock. L0 additionally carries adj_sort in
// blocks >= nbGemm (independent work, no inter-block sync).
struct GemmOut { _Float16* Y[4]; const float* bias[4]; int ldY[4]; };

#define LDP 136   // padded LDS row stride (bf16/fp16 elems)

__global__ __launch_bounds__(256, 4) void gemm_proj(
    const float* __restrict__ Xf,
    const _Float16* __restrict__ Hin,
    const float* __restrict__ Pbuf, float* __restrict__ bnpart,
    const float* __restrict__ gamma, const float* __restrict__ beta,
    float* __restrict__ scale, float* __restrict__ shift,
    int* __restrict__ sync,
    const unsigned short* __restrict__ WB4,   // fragment-ordered, 4 mats x 16384
    GemmOut go, int useBN, int N, int nbGemm,
    const int* __restrict__ rowptr, int* __restrict__ adj)
{
  __shared__ __align__(16) unsigned short xs[64 * LDP];

  if ((int)blockIdx.x >= nbGemm) {            // L0 only: fused adjacency sort
    adj_sort_body(rowptr, adj, ((int)blockIdx.x - nbGemm) * 16, N);
    return;
  }
  if (useBN)
    bn_prologue(Pbuf, bnpart, gamma, beta, scale, shift, sync, nbGemm, N);

  const int t = threadIdx.x;
  const int rowBase = blockIdx.x * 64;
  const int igc = (t & 15) * 8;

  if (useBN) {
    float4 sc0 = *reinterpret_cast<const float4*>(scale + igc);
    float4 sc1 = *reinterpret_cast<const float4*>(scale + igc + 4);
    float4 sh0 = *reinterpret_cast<const float4*>(shift + igc);
    float4 sh1 = *reinterpret_cast<const float4*>(shift + igc + 4);
#pragma unroll
    for (int j = 0; j < 4; ++j) {
      int v = t + 256 * j;
      int r = v >> 4;
      int grow = rowBase + r;
      ushort4 o0 = make_ushort4(0, 0, 0, 0), o1 = make_ushort4(0, 0, 0, 0);
      if (grow < N) {
        f16x8 hv = *reinterpret_cast<const f16x8*>(Hin + (size_t)grow * 128 + igc);
        o0.x = f2bf(fmaxf((float)hv[0] * sc0.x + sh0.x, 0.f));
        o0.y = f2bf(fmaxf((float)hv[1] * sc0.y + sh0.y, 0.f));
        o0.z = f2bf(fmaxf((float)hv[2] * sc0.z + sh0.z, 0.f));
        o0.w = f2bf(fmaxf((float)hv[3] * sc0.w + sh0.w, 0.f));
        o1.x = f2bf(fmaxf((float)hv[4] * sc1.x + sh1.x, 0.f));
        o1.y = f2bf(fmaxf((float)hv[5] * sc1.y + sh1.y, 0.f));
        o1.z = f2bf(fmaxf((float)hv[6] * sc1.z + sh1.z, 0.f));
        o1.w = f2bf(fmaxf((float)hv[7] * sc1.w + sh1.w, 0.f));
      }
      *reinterpret_cast<ushort4*>(&xs[r * LDP + igc]) = o0;
      *reinterpret_cast<ushort4*>(&xs[r * LDP + igc + 4]) = o1;
    }
  } else {
#pragma unroll
    for (int j = 0; j < 4; ++j) {
      int v = t + 256 * j;
      int r = v >> 4;
      int grow = rowBase + r;
      ushort4 o0 = make_ushort4(0, 0, 0, 0), o1 = make_ushort4(0, 0, 0, 0);
      if (grow < N) {
        float4 a = *reinterpret_cast<const float4*>(Xf + (size_t)grow * 128 + igc);
        float4 b = *reinterpret_cast<const float4*>(Xf + (size_t)grow * 128 + igc + 4);
        o0.x = f2bf(a.x); o0.y = f2bf(a.y); o0.z = f2bf(a.z); o0.w = f2bf(a.w);
        o1.x = f2bf(b.x); o1.y = f2bf(b.y); o1.z = f2bf(b.z); o1.w = f2bf(b.w);
      }
      *reinterpret_cast<ushort4*>(&xs[r * LDP + igc]) = o0;
      *reinterpret_cast<ushort4*>(&xs[r * LDP + igc + 4]) = o1;
    }
  }
  __syncthreads();

  const int wave = t >> 6;
  const int lane = t & 63;
  const int ln16 = lane & 15;
  const int quad = lane >> 4;
  const int r0 = wave * 16;

  bf16x8 afrag[4];
#pragma unroll
  for (int kk = 0; kk < 4; ++kk)
    afrag[kk] = *reinterpret_cast<const bf16x8*>(&xs[(r0 + ln16) * LDP + kk * 32 + quad * 8]);
  __syncthreads();   // xs becomes per-wave epilogue scratch below

  for (int proj = 0; proj < 4; ++proj) {
    const unsigned short* __restrict__ WB = WB4 + proj * 16384;
    const float* __restrict__ bias = go.bias[proj];

    f32x4 acc[8] = {};
#pragma unroll
    for (int kk = 0; kk < 4; ++kk) {
#pragma unroll
      for (int ct = 0; ct < 8; ++ct) {
        bf16x8 b = *reinterpret_cast<const bf16x8*>(WB + ((kk * 8 + ct) * 64 + lane) * 8);
        acc[ct] = __builtin_amdgcn_mfma_f32_16x16x32_bf16(afrag[kk], b, acc[ct], 0, 0, 0);
      }
    }

    _Float16* __restrict__ Yh = go.Y[proj];
    const int ldY = go.ldY[proj];
#pragma unroll
    for (int ct = 0; ct < 8; ++ct) {
      int col = ct * 16 + ln16;
      float bv = bias[col];
#pragma unroll
      for (int reg = 0; reg < 4; ++reg) {
        _Float16 hv = (_Float16)(acc[ct][reg] + bv);
        xs[(r0 + quad * 4 + reg) * LDP + col] = __builtin_bit_cast(unsigned short, hv);
      }
    }
#pragma unroll
    for (int pass = 0; pass < 4; ++pass) {
      int rl = (lane >> 4) + pass * 4;       // 0..15
      int grow = rowBase + r0 + rl;
      f16x8 v = *reinterpret_cast<const f16x8*>(&xs[(r0 + rl) * LDP + ln16 * 8]);
      if (grow < N)
        *reinterpret_cast<f16x8*>(&Yh[(size_t)grow * ldY + ln16 * 8]) = v;
    }
  }
}

// ---------------- fused per-node attention + BN partial stats ----------------
// 16 lanes per node, 16 nodes per 256-thread block. KV interleaved per node.
// No device-scope fences here (R5 lesson). H row hoisted above edge loop.
__global__ __launch_bounds__(256) void node_attn(
    const int* __restrict__ rowptr, const int* __restrict__ adj,
    const _Float16* __restrict__ Q, const _Float16* __restrict__ KV,
    _Float16* __restrict__ H, float* __restrict__ Pbuf, int N)
{
  __shared__ float lsum[16][132];
  __shared__ float lsq[16][132];
  int t = threadIdx.x;
  int w = t >> 4, lane = t & 15;
  int n = blockIdx.x * 16 + w;
  bool valid = n < N;
  int nn = valid ? n : 0;
  int p0 = 0, p1 = 0;
  if (valid) { p0 = rowptr[n]; p1 = rowptr[n + 1]; }
  int d = p1 - p0;

  f16x8 qv = *reinterpret_cast<const f16x8*>(Q + (size_t)nn * 128 + lane * 8);
  f16x8 hh = *reinterpret_cast<const f16x8*>(H + (size_t)nn * 128 + lane * 8);
  f16x2 q0 = {qv[0], qv[1]}, q1 = {qv[2], qv[3]}, q2 = {qv[4], qv[5]}, q3 = {qv[6], qv[7]};

  const float rsqd = 0.08838834764831845f;
  float m = -INFINITY, s = 0.f;
  float acc[8] = {};

#define EDGE1(SRC) do {                                                        \
    const _Float16* bp_ = KV + (size_t)(SRC) * 256 + lane * 8;                 \
    f16x8 ke_ = *reinterpret_cast<const f16x8*>(bp_);                          \
    f16x8 ve_ = *reinterpret_cast<const f16x8*>(bp_ + 128);                    \
    float dd_ = fdot2acc(q0, (f16x2){ke_[0], ke_[1]},                          \
                fdot2acc(q1, (f16x2){ke_[2], ke_[3]},                          \
                fdot2acc(q2, (f16x2){ke_[4], ke_[5]},                          \
                fdot2acc(q3, (f16x2){ke_[6], ke_[7]}, 0.f))));                 \
    for (int off_ = 8; off_; off_ >>= 1) dd_ += __shfl_xor(dd_, off_, 16);     \
    float ll_ = dd_ * rsqd;                                                    \
    float mn_ = fmaxf(m, ll_);                                                 \
    float sc_ = __expf(m - mn_);                                               \
    float w0_ = __expf(ll_ - mn_);                                             \
    for (int i_ = 0; i_ < 8; ++i_) acc[i_] = acc[i_] * sc_ + w0_ * (float)ve_[i_]; \
    s = s * sc_ + w0_;                                                         \
    m = mn_;                                                                   \
  } while (0)

  if (__builtin_expect(d <= 32, 1)) {
    int aLo = (lane < d) ? adj[p0 + lane] : 0;
    int aHi = (16 + lane < d) ? adj[p0 + 16 + lane] : 0;
    int e = 0;
    for (; e + 1 < d; e += 2) {
      int s0 = __shfl((e     < 16) ? aLo : aHi, (e    ) & 15, 16);
      int s1 = __shfl((e + 1 < 16) ? aLo : aHi, (e + 1) & 15, 16);
      const _Float16* b0 = KV + (size_t)s0 * 256 + lane * 8;
      const _Float16* b1 = KV + (size_t)s1 * 256 + lane * 8;
      f16x8 k0 = *reinterpret_cast<const f16x8*>(b0);
      f16x8 k1 = *reinterpret_cast<const f16x8*>(b1);
      f16x8 v0 = *reinterpret_cast<const f16x8*>(b0 + 128);
      f16x8 v1 = *reinterpret_cast<const f16x8*>(b1 + 128);
      float d0 = fdot2acc(q0, (f16x2){k0[0], k0[1]},
                 fdot2acc(q1, (f16x2){k0[2], k0[3]},
                 fdot2acc(q2, (f16x2){k0[4], k0[5]},
                 fdot2acc(q3, (f16x2){k0[6], k0[7]}, 0.f))));
      float d1 = fdot2acc(q0, (f16x2){k1[0], k1[1]},
                 fdot2acc(q1, (f16x2){k1[2], k1[3]},
                 fdot2acc(q2, (f16x2){k1[4], k1[5]},
                 fdot2acc(q3, (f16x2){k1[6], k1[7]}, 0.f))));
#pragma unroll
      for (int off = 8; off; off >>= 1) {
        d0 += __shfl_xor(d0, off, 16);
        d1 += __shfl_xor(d1, off, 16);
      }
      float l0 = d0 * rsqd;
      float l1 = d1 * rsqd;
      float mn = fmaxf(m, fmaxf(l0, l1));
      float sc = __expf(m - mn);
      float w0 = __expf(l0 - mn);
      float w1 = __expf(l1 - mn);
#pragma unroll
      for (int i = 0; i < 8; ++i)
        acc[i] = acc[i] * sc + w0 * (float)v0[i] + w1 * (float)v1[i];
      s = s * sc + w0 + w1;
      m = mn;
    }
    if (e < d) {
      int sE = __shfl((e < 16) ? aLo : aHi, e & 15, 16);
      EDGE1(sE);
    }
  } else {
    for (int p = p0; p < p1; ++p) { int sE = adj[p]; EDGE1(sE); }
  }
#undef EDGE1

  float h[8];
#pragma unroll
  for (int i = 0; i < 8; ++i) h[i] = 0.f;
  if (valid) {
    float inv = 1.0f / (s + 1e-16f);
    f16x8 ho;
#pragma unroll
    for (int i = 0; i < 8; ++i) {
      h[i] = (float)hh[i] + acc[i] * inv;
      ho[i] = (_Float16)h[i];
    }
    *reinterpret_cast<f16x8*>(H + (size_t)n * 128 + lane * 8) = ho;
  }

  // BN partial stats
#pragma unroll
  for (int i = 0; i < 8; i += 4) {
    float4 hv = make_float4(h[i], h[i + 1], h[i + 2], h[i + 3]);
    float4 h2 = make_float4(hv.x * hv.x, hv.y * hv.y, hv.z * hv.z, hv.w * hv.w);
    *reinterpret_cast<float4*>(&lsum[w][lane * 8 + i]) = hv;
    *reinterpret_cast<float4*>(&lsq[w][lane * 8 + i]) = h2;
  }
  __syncthreads();

  int f = t & 127;
  float a = 0.f;
  if (t < 128) {
#pragma unroll
    for (int n16 = 0; n16 < 16; ++n16) a += lsum[n16][f];
  } else {
#pragma unroll
    for (int n16 = 0; n16 < 16; ++n16) a += lsq[n16][f];
  }
  Pbuf[(size_t)blockIdx.x * 256 + t] = a;
}

// ---------------- deterministic parallel pooling (+ BN prologue of layer 2) --
__global__ __launch_bounds__(256) void pool_partial(
    const _Float16* __restrict__ H,
    const float* __restrict__ Pbuf, float* __restrict__ bnpart,
    const float* __restrict__ gamma, const float* __restrict__ beta,
    float* __restrict__ scale, float* __restrict__ shift,
    int* __restrict__ sync,
    const int* __restrict__ batch, float* __restrict__ partial, int N)
{
  bn_prologue(Pbuf, bnpart, gamma, beta, scale, shift, sync, POOL_CHUNKS, N);

  int f = threadIdx.x & 127, parity = threadIdx.x >> 7;
  int base = blockIdx.x * 64;
  int lim = min(base + 64, N);
  float sc = scale[f], sh = shift[f];
  int slot = ((blockIdx.x & 7) << 1) | parity;
  int curg = -1; float s = 0.f;
  for (int row = base + parity; row < lim; row += 2) {
    int g = batch[row];
    if (g != curg) {
      if (curg >= 0) partial[(size_t)((curg << 4) | slot) * 128 + f] = s;
      curg = g; s = 0.f;
    }
    s += fmaxf((float)H[(size_t)row * 128 + f] * sc + sh, 0.f);
  }
  if (curg >= 0) partial[(size_t)((curg << 4) | slot) * 128 + f] = s;
}

// ---------------- final linear (fused slot-reduce + classifier) --------------
__global__ __launch_bounds__(128) void final_linear(
    const float* __restrict__ partial, const int* __restrict__ batch,
    const float* __restrict__ Wlin, const float* __restrict__ blin,
    float* __restrict__ out, int N)
{
  __shared__ float pf[128];
  int g = blockIdx.x;
  int t = threadIdx.x;
  float s = 0.f;
#pragma unroll
  for (int sl = 0; sl < PSLOTS; ++sl)
    s += partial[(size_t)((g << 4) | sl) * 128 + t];
  pf[t] = s;
  __syncthreads();
  int lo = 0, hi = N;
  while (lo < hi) { int mid = (lo + hi) >> 1; if (batch[mid] < g) lo = mid + 1; else hi = mid; }
  int start = lo;
  hi = N;
  while (lo < hi) { int mid = (lo + hi) >> 1; if (batch[mid] < g + 1) lo = mid + 1; else hi = mid; }
  float inv = 1.0f / fmaxf((float)(lo - start), 1.f);
  if (t < 20) {
    float acc = 0.f;
#pragma unroll 4
    for (int i = 0; i < 128; ++i)
      acc += pf[i] * Wlin[i * 20 + t];
    out[g * 20 + t] = acc * inv + blin[t];
  }
}

// =============================================================================
extern "C" void kernel_launch(void* const* d_in, const int* in_sizes, int n_in,
                              void* d_out, int out_size, void* d_ws, size_t ws_size,
                              hipStream_t stream)
{
  const int N = N_NODES, E = N_EDGES, G = N_GRAPHS;

  const float* x = (const float*)d_in[0];
  const int* ei = (const int*)d_in[1];
  const int* batch = (const int*)d_in[2];
  const float* Wlin = (const float*)d_in[33];
  const float* blin = (const float*)d_in[34];

  char* ws = (char*)d_ws;
  size_t off = 0;
  auto alloc = [&](size_t bytes) -> void* {
    void* p = ws + off;
    off = (off + bytes + 255) & ~(size_t)255;
    return p;
  };
  unsigned short* WB = (unsigned short*)alloc(12 * 16384 * sizeof(unsigned short));
  _Float16* Qh  = (_Float16*)alloc((size_t)N * 128 * 2);
  _Float16* KVh = (_Float16*)alloc((size_t)N * 256 * 2);
  _Float16* Hh  = (_Float16*)alloc((size_t)N * 128 * 2);
  int* rowptr   = (int*)alloc((size_t)(N + 1) * 4);
  int* cursor   = (int*)alloc((size_t)N * 4);
  int* adj      = (int*)alloc((size_t)E * 4);
  int* partials = (int*)alloc((size_t)N_CHUNKS * 4);
  float* Pbuf   = (float*)alloc((size_t)ATTN_BLOCKS * 256 * 4);
  float* bnpart = (float*)alloc((size_t)64 * 256 * 4);
  float* scale  = (float*)alloc(128 * 4);
  float* shift  = (float*)alloc(128 * 4);
  int* deg      = (int*)alloc((size_t)N * 4);
  int* ctrl     = (int*)alloc(64 * 4);      // sync cells (zeroed in repack_zero)
  float* ppool  = (float*)alloc((size_t)G * PSLOTS * 128 * 4);

  int* snc[3] = { ctrl + 16, ctrl + 20, ctrl + 24 };  // [ticketA, ticketB, flag]

  WPtrs wp;
  for (int L = 0; L < 3; ++L) {
    wp.w[L * 4 + 0] = (const float*)d_in[3 + L * 10 + 0];  // Wq
    wp.w[L * 4 + 1] = (const float*)d_in[3 + L * 10 + 2];  // Wk
    wp.w[L * 4 + 2] = (const float*)d_in[3 + L * 10 + 4];  // Wv
    wp.w[L * 4 + 3] = (const float*)d_in[3 + L * 10 + 6];  // Ws
  }

  repack_zero<<<768, 256, 0, stream>>>(wp, WB, deg, ctrl, ppool, N);
  deg_count<<<(E + 255) / 256, 256, 0, stream>>>(ei, deg, E);
  scan_sum<<<N_CHUNKS, 256, 0, stream>>>(deg, partials, N);
  scan_apply<<<N_CHUNKS, 256, 0, stream>>>(deg, partials, rowptr, cursor, N, E);
  csr_scatter<<<(E + 255) / 256, 256, 0, stream>>>(ei, cursor, adj, E);

  for (int L = 0; L < 3; ++L) {
    GemmOut go;
    go.Y[0] = Qh;        go.ldY[0] = 128;
    go.Y[1] = KVh;       go.ldY[1] = 256;   // K at +0
    go.Y[2] = KVh + 128; go.ldY[2] = 256;   // V at +128
    go.Y[3] = Hh;        go.ldY[3] = 128;
    go.bias[0] = (const float*)d_in[3 + L * 10 + 1];
    go.bias[1] = (const float*)d_in[3 + L * 10 + 3];
    go.bias[2] = (const float*)d_in[3 + L * 10 + 5];
    go.bias[3] = (const float*)d_in[3 + L * 10 + 7];

    if (L == 0) {
      // grid = gemm blocks + adj_sort blocks (independent work, one dispatch)
      gemm_proj<<<NB_GEMM + ATTN_BLOCKS, 256, 0, stream>>>(
          x, Hh, nullptr, nullptr, nullptr, nullptr, scale, shift, snc[0],
          WB, go, 0, N, NB_GEMM, rowptr, adj);
    } else {
      gemm_proj<<<NB_GEMM, 256, 0, stream>>>(
          x, Hh, Pbuf, bnpart,
          (const float*)d_in[3 + (L - 1) * 10 + 8],
          (const float*)d_in[3 + (L - 1) * 10 + 9],
          scale, shift, snc[L - 1],
          WB + L * 4 * 16384, go, 1, N, NB_GEMM, nullptr, nullptr);
    }

    node_attn<<<ATTN_BLOCKS, 256, 0, stream>>>(rowptr, adj, Qh, KVh, Hh, Pbuf, N);
  }

  pool_partial<<<POOL_CHUNKS, 256, 0, stream>>>(
      Hh, Pbuf, bnpart,
      (const float*)d_in[3 + 2 * 10 + 8],
      (const float*)d_in[3 + 2 * 10 + 9],
      scale, shift, snc[2], batch, ppool, N);
  final_linear<<<G, 128, 0, stream>>>(ppool, batch, Wlin, blin, (float*)d_out, N);
}

// Round 9
// 425.669 us; speedup vs baseline: 2.1452x; 2.1452x over previous
//
#include <hip/hip_runtime.h>

#define N_NODES 50000
#define N_EDGES 400000
#define DH 128
#define N_GRAPHS 256

#define SCAN_CHUNK 512
#define N_CHUNKS ((N_NODES + SCAN_CHUNK - 1) / SCAN_CHUNK)   // 98
#define ATTN_BLOCKS ((N_NODES + 15) / 16)                    // 3125
#define POOL_CHUNKS ((N_NODES + 63) / 64)                    // 782
#define PSLOTS 16

typedef __bf16 bf16x8 __attribute__((ext_vector_type(8)));
typedef float f32x4 __attribute__((ext_vector_type(4)));
typedef _Float16 f16x2 __attribute__((ext_vector_type(2)));
typedef _Float16 f16x8 __attribute__((ext_vector_type(8)));

#define DEV __device__ __forceinline__

#if defined(__has_builtin)
#if __has_builtin(__builtin_amdgcn_fdot2)
#define HAS_FDOT2 1
#endif
#endif

DEV float fdot2acc(f16x2 a, f16x2 b, float c) {
#ifdef HAS_FDOT2
  return __builtin_amdgcn_fdot2(a, b, c, false);
#else
  return (float)a.x * (float)b.x + (float)a.y * (float)b.y + c;
#endif
}

DEV unsigned short f2bf(float f) {
  union { float f; unsigned int i; } v; v.f = f;
  unsigned int x = v.i;
  unsigned int r = (x + 0x7fffu + ((x >> 16) & 1u)) >> 16;
  return (unsigned short)r;
}

struct WPtrs { const float* w[12]; };

// ---- setup: weight repack + zero deg/tickets/ppool (replaces repack+memset) -
// R8-verified component: no sync, runs at full occupancy.
__global__ __launch_bounds__(256) void repack_zero(
    WPtrs wp, unsigned short* __restrict__ WB,
    int* __restrict__ deg, int* __restrict__ ctrl, float* __restrict__ ppool,
    int N)
{
  const int T = 768 * 256;
  int gtid = blockIdx.x * 256 + threadIdx.x;
  for (int m = gtid; m < 12 * 16384; m += T) {
    int mat = m >> 14;
    int mm = m & 16383;
    int j = mm & 7;
    int lane = (mm >> 3) & 63;
    int ct = (mm >> 9) & 7;
    int kk = mm >> 12;
    int i = kk * 32 + (lane >> 4) * 8 + j;
    int o = ct * 16 + (lane & 15);
    WB[m] = f2bf(wp.w[mat][i * 128 + o]);
  }
  for (int i = gtid; i < N; i += T) deg[i] = 0;
  if (gtid < 64) ctrl[gtid] = 0;
  for (int i = gtid; i < N_GRAPHS * PSLOTS * 128; i += T) ppool[i] = 0.f;
}

// ---------------- CSR build (split kernels: full occupancy per phase) --------
// R6 lesson: grid-barrier fusion caps occupancy (205 us). R8 lesson: wide
// single-cell tickets serialize ~150-250ns/atomic across XCDs (180 us for
// 782 blocks). Split dispatches at ~4us each are the cheap option.
__global__ void deg_count(const int* __restrict__ ei, int* __restrict__ deg, int E) {
  int e = blockIdx.x * 256 + threadIdx.x;
  if (e < E) atomicAdd(&deg[ei[E + e]], 1);
}

__global__ __launch_bounds__(256) void scan_sum(const int* __restrict__ deg,
                                                int* __restrict__ partials, int N) {
  __shared__ int red[256];
  int b = blockIdx.x, t = threadIdx.x;
  int base = b * SCAN_CHUNK + t * 2;
  int s = 0;
  if (base + 1 < N) { int2 v = *reinterpret_cast<const int2*>(deg + base); s = v.x + v.y; }
  else if (base < N) s = deg[base];
  red[t] = s;
  __syncthreads();
  for (int off = 128; off; off >>= 1) {
    if (t < off) red[t] += red[t + off];
    __syncthreads();
  }
  if (t == 0) partials[b] = red[0];
}

__global__ __launch_bounds__(256) void scan_apply(const int* __restrict__ deg,
                                                  const int* __restrict__ partials,
                                                  int* __restrict__ rowptr,
                                                  int* __restrict__ cursor, int N, int E) {
  __shared__ int s[256];
  __shared__ int prefSh;
  int b = blockIdx.x, t = threadIdx.x;

  s[t] = (t < b) ? partials[t] : 0;    // b <= 97 < 256
  __syncthreads();
  for (int off = 128; off; off >>= 1) {
    if (t < off) s[t] += s[t + off];
    __syncthreads();
  }
  if (t == 0) prefSh = s[0];
  __syncthreads();
  int pref = prefSh;
  __syncthreads();

  int base = b * SCAN_CHUNK + t * 2;
  int d0 = 0, d1 = 0;
  if (base + 1 < N) { int2 v = *reinterpret_cast<const int2*>(deg + base); d0 = v.x; d1 = v.y; }
  else if (base < N) d0 = deg[base];
  int local = d0 + d1;
  s[t] = local;
  __syncthreads();
  for (int off = 1; off < 256; off <<= 1) {
    int o = (t >= off) ? s[t - off] : 0;
    __syncthreads();
    s[t] += o;
    __syncthreads();
  }
  int offp = pref + s[t] - local;
  if (base < N)     { rowptr[base] = offp;          cursor[base] = offp; }
  if (base + 1 < N) { rowptr[base + 1] = offp + d0; cursor[base + 1] = offp + d0; }
  if (b == 0 && t == 0) rowptr[N] = E;
}

__global__ void csr_scatter(const int* __restrict__ ei, int* __restrict__ cursor,
                            int* __restrict__ adj, int E) {
  int e = blockIdx.x * 256 + threadIdx.x;
  if (e < E) {
    int dst = ei[E + e];
    int pos = atomicAdd(&cursor[dst], 1);
    adj[pos] = ei[e];
  }
}

// Canonicalize adjacency order (atomic scatter lands edges in nondeterministic
// order; online-softmax rounding is order-sensitive). Parallel rank-sort:
// one 16-lane group per row, each lane owns up to 2 elements (cap 32 >> max
// degree ~28 for Poisson(8)); rank = #smaller + index tie-break (== stable
// ascending sort), scatter via 128B of LDS.
__global__ __launch_bounds__(256) void adj_sort16(const int* __restrict__ rowptr,
                                                  int* __restrict__ adj, int N) {
  __shared__ int buf[16 * 32];
  int t = threadIdx.x;
  int g = t >> 4, l = t & 15;
  int n = blockIdx.x * 16 + g;
  bool valid = n < N;
  int p0 = 0, d = 0;
  if (valid) { p0 = rowptr[n]; d = rowptr[n + 1] - p0; }
  if (__builtin_expect(d > 32, 0)) {
    if (l == 0) {                      // rare fallback: serial insertion sort
      for (int i = p0 + 1; i < p0 + d; ++i) {
        int v = adj[i]; int j = i - 1;
        while (j >= p0 && adj[j] > v) { adj[j + 1] = adj[j]; --j; }
        adj[j + 1] = v;
      }
    }
    d = 0;                             // skip parallel path, keep convergence
  }
  int a0 = (l < d) ? adj[p0 + l] : 0x7fffffff;
  int a1 = (16 + l < d) ? adj[p0 + 16 + l] : 0x7fffffff;
  int r0 = 0, r1 = 0;
#pragma unroll
  for (int i = 0; i < 16; ++i) {
    int v0 = __shfl(a0, i, 16);
    int v1 = __shfl(a1, i, 16);
    r0 += (v0 < a0) || (v0 == a0 && i < l);
    r0 += (v1 < a0);
    r1 += (v0 <= a1);
    r1 += (v1 < a1) || (v1 == a1 && i < l);
  }
  if (l < d)      buf[g * 32 + r0] = a0;
  if (16 + l < d) buf[g * 32 + r1] = a1;
  __syncthreads();
  if (l < d)      adj[p0 + l]      = buf[g * 32 + l];
  if (16 + l < d) adj[p0 + 16 + l] = buf[g * 32 + 16 + l];
}

// ---------------- fused 4-projection GEMM: {Q,K,V,H} = BN(X) @ W_p + b_p -----
struct GemmOut { _Float16* Y[4]; const float* bias[4]; int ldY[4]; };

#define LDP 136   // padded LDS row stride (bf16/fp16 elems)

__global__ __launch_bounds__(256) void gemm_proj(
    const float* __restrict__ Xf,
    const _Float16* __restrict__ Hin,
    const float* __restrict__ scale, const float* __restrict__ shift,
    const unsigned short* __restrict__ WB4,   // fragment-ordered, 4 mats x 16384
    GemmOut go, int useBN, int N)
{
  __shared__ __align__(16) unsigned short xs[64 * LDP];

  const int t = threadIdx.x;
  const int rowBase = blockIdx.x * 64;
  const int igc = (t & 15) * 8;

  if (useBN) {
    float4 sc0 = *reinterpret_cast<const float4*>(scale + igc);
    float4 sc1 = *reinterpret_cast<const float4*>(scale + igc + 4);
    float4 sh0 = *reinterpret_cast<const float4*>(shift + igc);
    float4 sh1 = *reinterpret_cast<const float4*>(shift + igc + 4);
#pragma unroll
    for (int j = 0; j < 4; ++j) {
      int v = t + 256 * j;
      int r = v >> 4;
      int grow = rowBase + r;
      ushort4 o0 = make_ushort4(0, 0, 0, 0), o1 = make_ushort4(0, 0, 0, 0);
      if (grow < N) {
        f16x8 hv = *reinterpret_cast<const f16x8*>(Hin + (size_t)grow * 128 + igc);
        o0.x = f2bf(fmaxf((float)hv[0] * sc0.x + sh0.x, 0.f));
        o0.y = f2bf(fmaxf((float)hv[1] * sc0.y + sh0.y, 0.f));
        o0.z = f2bf(fmaxf((float)hv[2] * sc0.z + sh0.z, 0.f));
        o0.w = f2bf(fmaxf((float)hv[3] * sc0.w + sh0.w, 0.f));
        o1.x = f2bf(fmaxf((float)hv[4] * sc1.x + sh1.x, 0.f));
        o1.y = f2bf(fmaxf((float)hv[5] * sc1.y + sh1.y, 0.f));
        o1.z = f2bf(fmaxf((float)hv[6] * sc1.z + sh1.z, 0.f));
        o1.w = f2bf(fmaxf((float)hv[7] * sc1.w + sh1.w, 0.f));
      }
      *reinterpret_cast<ushort4*>(&xs[r * LDP + igc]) = o0;
      *reinterpret_cast<ushort4*>(&xs[r * LDP + igc + 4]) = o1;
    }
  } else {
#pragma unroll
    for (int j = 0; j < 4; ++j) {
      int v = t + 256 * j;
      int r = v >> 4;
      int grow = rowBase + r;
      ushort4 o0 = make_ushort4(0, 0, 0, 0), o1 = make_ushort4(0, 0, 0, 0);
      if (grow < N) {
        float4 a = *reinterpret_cast<const float4*>(Xf + (size_t)grow * 128 + igc);
        float4 b = *reinterpret_cast<const float4*>(Xf + (size_t)grow * 128 + igc + 4);
        o0.x = f2bf(a.x); o0.y = f2bf(a.y); o0.z = f2bf(a.z); o0.w = f2bf(a.w);
        o1.x = f2bf(b.x); o1.y = f2bf(b.y); o1.z = f2bf(b.z); o1.w = f2bf(b.w);
      }
      *reinterpret_cast<ushort4*>(&xs[r * LDP + igc]) = o0;
      *reinterpret_cast<ushort4*>(&xs[r * LDP + igc + 4]) = o1;
    }
  }
  __syncthreads();

  const int wave = t >> 6;
  const int lane = t & 63;
  const int ln16 = lane & 15;
  const int quad = lane >> 4;
  const int r0 = wave * 16;

  bf16x8 afrag[4];
#pragma unroll
  for (int kk = 0; kk < 4; ++kk)
    afrag[kk] = *reinterpret_cast<const bf16x8*>(&xs[(r0 + ln16) * LDP + kk * 32 + quad * 8]);
  __syncthreads();   // xs becomes per-wave epilogue scratch below

  for (int proj = 0; proj < 4; ++proj) {
    const unsigned short* __restrict__ WB = WB4 + proj * 16384;
    const float* __restrict__ bias = go.bias[proj];

    f32x4 acc[8] = {};
#pragma unroll
    for (int kk = 0; kk < 4; ++kk) {
#pragma unroll
      for (int ct = 0; ct < 8; ++ct) {
        bf16x8 b = *reinterpret_cast<const bf16x8*>(WB + ((kk * 8 + ct) * 64 + lane) * 8);
        acc[ct] = __builtin_amdgcn_mfma_f32_16x16x32_bf16(afrag[kk], b, acc[ct], 0, 0, 0);
      }
    }

    _Float16* __restrict__ Yh = go.Y[proj];
    const int ldY = go.ldY[proj];
#pragma unroll
    for (int ct = 0; ct < 8; ++ct) {
      int col = ct * 16 + ln16;
      float bv = bias[col];
#pragma unroll
      for (int reg = 0; reg < 4; ++reg) {
        _Float16 hv = (_Float16)(acc[ct][reg] + bv);
        xs[(r0 + quad * 4 + reg) * LDP + col] = __builtin_bit_cast(unsigned short, hv);
      }
    }
#pragma unroll
    for (int pass = 0; pass < 4; ++pass) {
      int rl = (lane >> 4) + pass * 4;       // 0..15
      int grow = rowBase + r0 + rl;
      f16x8 v = *reinterpret_cast<const f16x8*>(&xs[(r0 + rl) * LDP + ln16 * 8]);
      if (grow < N)
        *reinterpret_cast<f16x8*>(&Yh[(size_t)grow * ldY + ln16 * 8]) = v;
    }
  }
}

// ---------------- fused per-node attention + BN partial stats ----------------
// 16 lanes per node, 16 nodes per 256-thread block. KV interleaved per node.
// No device-scope fences/tickets here (R5/R8 lessons). H row hoisted.
__global__ __launch_bounds__(256) void node_attn(
    const int* __restrict__ rowptr, const int* __restrict__ adj,
    const _Float16* __restrict__ Q, const _Float16* __restrict__ KV,
    _Float16* __restrict__ H, float* __restrict__ Pbuf, int N)
{
  __shared__ float lsum[16][132];
  __shared__ float lsq[16][132];
  int t = threadIdx.x;
  int w = t >> 4, lane = t & 15;
  int n = blockIdx.x * 16 + w;
  bool valid = n < N;
  int nn = valid ? n : 0;
  int p0 = 0, p1 = 0;
  if (valid) { p0 = rowptr[n]; p1 = rowptr[n + 1]; }
  int d = p1 - p0;

  f16x8 qv = *reinterpret_cast<const f16x8*>(Q + (size_t)nn * 128 + lane * 8);
  f16x8 hh = *reinterpret_cast<const f16x8*>(H + (size_t)nn * 128 + lane * 8);
  f16x2 q0 = {qv[0], qv[1]}, q1 = {qv[2], qv[3]}, q2 = {qv[4], qv[5]}, q3 = {qv[6], qv[7]};

  const float rsqd = 0.08838834764831845f;
  float m = -INFINITY, s = 0.f;
  float acc[8] = {};

#define EDGE1(SRC) do {                                                        \
    const _Float16* bp_ = KV + (size_t)(SRC) * 256 + lane * 8;                 \
    f16x8 ke_ = *reinterpret_cast<const f16x8*>(bp_);                          \
    f16x8 ve_ = *reinterpret_cast<const f16x8*>(bp_ + 128);                    \
    float dd_ = fdot2acc(q0, (f16x2){ke_[0], ke_[1]},                          \
                fdot2acc(q1, (f16x2){ke_[2], ke_[3]},                          \
                fdot2acc(q2, (f16x2){ke_[4], ke_[5]},                          \
                fdot2acc(q3, (f16x2){ke_[6], ke_[7]}, 0.f))));                 \
    for (int off_ = 8; off_; off_ >>= 1) dd_ += __shfl_xor(dd_, off_, 16);     \
    float ll_ = dd_ * rsqd;                                                    \
    float mn_ = fmaxf(m, ll_);                                                 \
    float sc_ = __expf(m - mn_);                                               \
    float w0_ = __expf(ll_ - mn_);                                             \
    for (int i_ = 0; i_ < 8; ++i_) acc[i_] = acc[i_] * sc_ + w0_ * (float)ve_[i_]; \
    s = s * sc_ + w0_;                                                         \
    m = mn_;                                                                   \
  } while (0)

  if (__builtin_expect(d <= 32, 1)) {
    int aLo = (lane < d) ? adj[p0 + lane] : 0;
    int aHi = (16 + lane < d) ? adj[p0 + 16 + lane] : 0;
    int e = 0;
    for (; e + 1 < d; e += 2) {
      int s0 = __shfl((e     < 16) ? aLo : aHi, (e    ) & 15, 16);
      int s1 = __shfl((e + 1 < 16) ? aLo : aHi, (e + 1) & 15, 16);
      const _Float16* b0 = KV + (size_t)s0 * 256 + lane * 8;
      const _Float16* b1 = KV + (size_t)s1 * 256 + lane * 8;
      f16x8 k0 = *reinterpret_cast<const f16x8*>(b0);
      f16x8 k1 = *reinterpret_cast<const f16x8*>(b1);
      f16x8 v0 = *reinterpret_cast<const f16x8*>(b0 + 128);
      f16x8 v1 = *reinterpret_cast<const f16x8*>(b1 + 128);
      float d0 = fdot2acc(q0, (f16x2){k0[0], k0[1]},
                 fdot2acc(q1, (f16x2){k0[2], k0[3]},
                 fdot2acc(q2, (f16x2){k0[4], k0[5]},
                 fdot2acc(q3, (f16x2){k0[6], k0[7]}, 0.f))));
      float d1 = fdot2acc(q0, (f16x2){k1[0], k1[1]},
                 fdot2acc(q1, (f16x2){k1[2], k1[3]},
                 fdot2acc(q2, (f16x2){k1[4], k1[5]},
                 fdot2acc(q3, (f16x2){k1[6], k1[7]}, 0.f))));
#pragma unroll
      for (int off = 8; off; off >>= 1) {
        d0 += __shfl_xor(d0, off, 16);
        d1 += __shfl_xor(d1, off, 16);
      }
      float l0 = d0 * rsqd;
      float l1 = d1 * rsqd;
      float mn = fmaxf(m, fmaxf(l0, l1));
      float sc = __expf(m - mn);
      float w0 = __expf(l0 - mn);
      float w1 = __expf(l1 - mn);
#pragma unroll
      for (int i = 0; i < 8; ++i)
        acc[i] = acc[i] * sc + w0 * (float)v0[i] + w1 * (float)v1[i];
      s = s * sc + w0 + w1;
      m = mn;
    }
    if (e < d) {
      int sE = __shfl((e < 16) ? aLo : aHi, e & 15, 16);
      EDGE1(sE);
    }
  } else {
    for (int p = p0; p < p1; ++p) { int sE = adj[p]; EDGE1(sE); }
  }
#undef EDGE1

  float h[8];
#pragma unroll
  for (int i = 0; i < 8; ++i) h[i] = 0.f;
  if (valid) {
    float inv = 1.0f / (s + 1e-16f);
    f16x8 ho;
#pragma unroll
    for (int i = 0; i < 8; ++i) {
      h[i] = (float)hh[i] + acc[i] * inv;
      ho[i] = (_Float16)h[i];
    }
    *reinterpret_cast<f16x8*>(H + (size_t)n * 128 + lane * 8) = ho;
  }

  // BN partial stats
#pragma unroll
  for (int i = 0; i < 8; i += 4) {
    float4 hv = make_float4(h[i], h[i + 1], h[i + 2], h[i + 3]);
    float4 h2 = make_float4(hv.x * hv.x, hv.y * hv.y, hv.z * hv.z, hv.w * hv.w);
    *reinterpret_cast<float4*>(&lsum[w][lane * 8 + i]) = hv;
    *reinterpret_cast<float4*>(&lsq[w][lane * 8 + i]) = h2;
  }
  __syncthreads();

  int f = t & 127;
  float a = 0.f;
  if (t < 128) {
#pragma unroll
    for (int n16 = 0; n16 < 16; ++n16) a += lsum[n16][f];
  } else {
#pragma unroll
    for (int n16 = 0; n16 < 16; ++n16) a += lsq[n16][f];
  }
  Pbuf[(size_t)blockIdx.x * 256 + t] = a;
}

// ---------------- fused BN reduce (ticket: last of 64 blocks finishes) -------
// 64 tickets on one cell ≈ 10us worst case — acceptable (R8 rule: ≲64 only).
__global__ __launch_bounds__(256) void bn_fused(
    const float* __restrict__ Pbuf, float* __restrict__ bnpart,
    const float* __restrict__ gamma, const float* __restrict__ beta,
    float* __restrict__ scale, float* __restrict__ shift,
    int* __restrict__ ticket, int N)
{
  __shared__ float red[256];
  __shared__ int amLast;
  int t = threadIdx.x;
  {
    float s0 = 0.f, s1 = 0.f, s2 = 0.f, s3 = 0.f;
    int r = blockIdx.x;
    for (; r + 192 < ATTN_BLOCKS; r += 256) {
      s0 += Pbuf[(size_t)(r      ) * 256 + t];
      s1 += Pbuf[(size_t)(r +  64) * 256 + t];
      s2 += Pbuf[(size_t)(r + 128) * 256 + t];
      s3 += Pbuf[(size_t)(r + 192) * 256 + t];
    }
    for (; r < ATTN_BLOCKS; r += 64) s0 += Pbuf[(size_t)r * 256 + t];
    bnpart[blockIdx.x * 256 + t] = s0 + s1 + s2 + s3;
  }
  __threadfence();                       // release partials (device scope)
  if (t == 0) amLast = (atomicAdd(ticket, 1) == 63);
  __syncthreads();
  if (!amLast) return;
  __threadfence();                       // acquire all blocks' partials

  float s0 = 0.f, s1 = 0.f, s2 = 0.f, s3 = 0.f;
#pragma unroll
  for (int r = 0; r < 64; r += 4) {
    s0 += bnpart[(r + 0) * 256 + t];
    s1 += bnpart[(r + 1) * 256 + t];
    s2 += bnpart[(r + 2) * 256 + t];
    s3 += bnpart[(r + 3) * 256 + t];
  }
  red[t] = s0 + s1 + s2 + s3;
  __syncthreads();
  if (t < 128) {
    float mean = red[t] / (float)N;
    float var = red[t + 128] / (float)N - mean * mean;
    var = fmaxf(var, 0.f);
    float sc = gamma[t] * rsqrtf(var + 1e-5f);
    scale[t] = sc;
    shift[t] = beta[t] - mean * sc;
  }
}

// ---------------- deterministic parallel pooling ----------------------------
__global__ __launch_bounds__(256) void pool_partial(
    const _Float16* __restrict__ H, const float* __restrict__ scale,
    const float* __restrict__ shift, const int* __restrict__ batch,
    float* __restrict__ partial, int N)
{
  int f = threadIdx.x & 127, parity = threadIdx.x >> 7;
  int base = blockIdx.x * 64;
  int lim = min(base + 64, N);
  float sc = scale[f], sh = shift[f];
  int slot = ((blockIdx.x & 7) << 1) | parity;
  int curg = -1; float s = 0.f;
  for (int row = base + parity; row < lim; row += 2) {
    int g = batch[row];
    if (g != curg) {
      if (curg >= 0) partial[(size_t)((curg << 4) | slot) * 128 + f] = s;
      curg = g; s = 0.f;
    }
    s += fmaxf((float)H[(size_t)row * 128 + f] * sc + sh, 0.f);
  }
  if (curg >= 0) partial[(size_t)((curg << 4) | slot) * 128 + f] = s;
}

// ---------------- final linear (fused slot-reduce + classifier) --------------
__global__ __launch_bounds__(128) void final_linear(
    const float* __restrict__ partial, const int* __restrict__ batch,
    const float* __restrict__ Wlin, const float* __restrict__ blin,
    float* __restrict__ out, int N)
{
  __shared__ float pf[128];
  int g = blockIdx.x;
  int t = threadIdx.x;
  float s = 0.f;
#pragma unroll
  for (int sl = 0; sl < PSLOTS; ++sl)
    s += partial[(size_t)((g << 4) | sl) * 128 + t];
  pf[t] = s;
  __syncthreads();
  int lo = 0, hi = N;
  while (lo < hi) { int mid = (lo + hi) >> 1; if (batch[mid] < g) lo = mid + 1; else hi = mid; }
  int start = lo;
  hi = N;
  while (lo < hi) { int mid = (lo + hi) >> 1; if (batch[mid] < g + 1) lo = mid + 1; else hi = mid; }
  float inv = 1.0f / fmaxf((float)(lo - start), 1.f);
  if (t < 20) {
    float acc = 0.f;
#pragma unroll 4
    for (int i = 0; i < 128; ++i)
      acc += pf[i] * Wlin[i * 20 + t];
    out[g * 20 + t] = acc * inv + blin[t];
  }
}

// =============================================================================
extern "C" void kernel_launch(void* const* d_in, const int* in_sizes, int n_in,
                              void* d_out, int out_size, void* d_ws, size_t ws_size,
                              hipStream_t stream)
{
  const int N = N_NODES, E = N_EDGES, G = N_GRAPHS;

  const float* x = (const float*)d_in[0];
  const int* ei = (const int*)d_in[1];
  const int* batch = (const int*)d_in[2];
  const float* Wlin = (const float*)d_in[33];
  const float* blin = (const float*)d_in[34];

  char* ws = (char*)d_ws;
  size_t off = 0;
  auto alloc = [&](size_t bytes) -> void* {
    void* p = ws + off;
    off = (off + bytes + 255) & ~(size_t)255;
    return p;
  };
  unsigned short* WB = (unsigned short*)alloc(12 * 16384 * sizeof(unsigned short));
  _Float16* Qh  = (_Float16*)alloc((size_t)N * 128 * 2);
  _Float16* KVh = (_Float16*)alloc((size_t)N * 256 * 2);
  _Float16* Hh  = (_Float16*)alloc((size_t)N * 128 * 2);
  int* rowptr   = (int*)alloc((size_t)(N + 1) * 4);
  int* cursor   = (int*)alloc((size_t)N * 4);
  int* adj      = (int*)alloc((size_t)E * 4);
  int* partials = (int*)alloc((size_t)N_CHUNKS * 4);
  float* Pbuf   = (float*)alloc((size_t)ATTN_BLOCKS * 256 * 4);
  float* bnpart = (float*)alloc((size_t)64 * 256 * 4);
  float* scale  = (float*)alloc(128 * 4);
  float* shift  = (float*)alloc(128 * 4);
  int* deg      = (int*)alloc((size_t)N * 4);
  int* ctrl     = (int*)alloc(64 * 4);      // tickets (zeroed in repack_zero)
  float* ppool  = (float*)alloc((size_t)G * PSLOTS * 128 * 4);

  WPtrs wp;
  for (int L = 0; L < 3; ++L) {
    wp.w[L * 4 + 0] = (const float*)d_in[3 + L * 10 + 0];  // Wq
    wp.w[L * 4 + 1] = (const float*)d_in[3 + L * 10 + 2];  // Wk
    wp.w[L * 4 + 2] = (const float*)d_in[3 + L * 10 + 4];  // Wv
    wp.w[L * 4 + 3] = (const float*)d_in[3 + L * 10 + 6];  // Ws
  }

  repack_zero<<<768, 256, 0, stream>>>(wp, WB, deg, ctrl, ppool, N);
  deg_count<<<(E + 255) / 256, 256, 0, stream>>>(ei, deg, E);
  scan_sum<<<N_CHUNKS, 256, 0, stream>>>(deg, partials, N);
  scan_apply<<<N_CHUNKS, 256, 0, stream>>>(deg, partials, rowptr, cursor, N, E);
  csr_scatter<<<(E + 255) / 256, 256, 0, stream>>>(ei, cursor, adj, E);
  adj_sort16<<<ATTN_BLOCKS, 256, 0, stream>>>(rowptr, adj, N);

  for (int L = 0; L < 3; ++L) {
    GemmOut go;
    go.Y[0] = Qh;        go.ldY[0] = 128;
    go.Y[1] = KVh;       go.ldY[1] = 256;   // K at +0
    go.Y[2] = KVh + 128; go.ldY[2] = 256;   // V at +128
    go.Y[3] = Hh;        go.ldY[3] = 128;
    go.bias[0] = (const float*)d_in[3 + L * 10 + 1];
    go.bias[1] = (const float*)d_in[3 + L * 10 + 3];
    go.bias[2] = (const float*)d_in[3 + L * 10 + 5];
    go.bias[3] = (const float*)d_in[3 + L * 10 + 7];
    gemm_proj<<<(N + 63) / 64, 256, 0, stream>>>(
        x, Hh, scale, shift, WB + L * 4 * 16384, go, (L > 0) ? 1 : 0, N);

    node_attn<<<ATTN_BLOCKS, 256, 0, stream>>>(rowptr, adj, Qh, KVh, Hh, Pbuf, N);

    bn_fused<<<64, 256, 0, stream>>>(Pbuf, bnpart,
        (const float*)d_in[3 + L * 10 + 8],
        (const float*)d_in[3 + L * 10 + 9],
        scale, shift, ctrl + L, N);

    if (L == 2) {
      pool_partial<<<POOL_CHUNKS, 256, 0, stream>>>(Hh, scale, shift, batch, ppool, N);
      final_linear<<<G, 128, 0, stream>>>(ppool, batch, Wlin, blin, (float*)d_out, N);
    }
  }
}

// Round 10
// 419.382 us; speedup vs baseline: 2.1774x; 1.0150x over previous
//
#include <hip/hip_runtime.h>

#define N_NODES 50000
#define N_EDGES 400000
#define DH 128
#define N_GRAPHS 256

#define SCAN_CHUNK 512
#define N_CHUNKS ((N_NODES + SCAN_CHUNK - 1) / SCAN_CHUNK)   // 98
#define ATTN_BLOCKS ((N_NODES + 15) / 16)                    // 3125
#define POOL_CHUNKS ((N_NODES + 63) / 64)                    // 782
#define NB_GEMM ((N_NODES + 63) / 64)                        // 782
#define PSLOTS 16

typedef __bf16 bf16x8 __attribute__((ext_vector_type(8)));
typedef float f32x4 __attribute__((ext_vector_type(4)));
typedef _Float16 f16x2 __attribute__((ext_vector_type(2)));
typedef _Float16 f16x8 __attribute__((ext_vector_type(8)));

#define DEV __device__ __forceinline__

#if defined(__has_builtin)
#if __has_builtin(__builtin_amdgcn_fdot2)
#define HAS_FDOT2 1
#endif
#endif

DEV float fdot2acc(f16x2 a, f16x2 b, float c) {
#ifdef HAS_FDOT2
  return __builtin_amdgcn_fdot2(a, b, c, false);
#else
  return (float)a.x * (float)b.x + (float)a.y * (float)b.y + c;
#endif
}

DEV unsigned short f2bf(float f) {
  union { float f; unsigned int i; } v; v.f = f;
  unsigned int x = v.i;
  unsigned int r = (x + 0x7fffu + ((x >> 16) & 1u)) >> 16;
  return (unsigned short)r;
}

struct WPtrs { const float* w[12]; };

// ---- setup: weight repack + zero deg/tickets/ppool (replaces repack+memset) -
__global__ __launch_bounds__(256) void repack_zero(
    WPtrs wp, unsigned short* __restrict__ WB,
    int* __restrict__ deg, int* __restrict__ ctrl, float* __restrict__ ppool,
    int N)
{
  const int T = 768 * 256;
  int gtid = blockIdx.x * 256 + threadIdx.x;
  for (int m = gtid; m < 12 * 16384; m += T) {
    int mat = m >> 14;
    int mm = m & 16383;
    int j = mm & 7;
    int lane = (mm >> 3) & 63;
    int ct = (mm >> 9) & 7;
    int kk = mm >> 12;
    int i = kk * 32 + (lane >> 4) * 8 + j;
    int o = ct * 16 + (lane & 15);
    WB[m] = f2bf(wp.w[mat][i * 128 + o]);
  }
  for (int i = gtid; i < N; i += T) deg[i] = 0;
  if (gtid < 64) ctrl[gtid] = 0;
  for (int i = gtid; i < N_GRAPHS * PSLOTS * 128; i += T) ppool[i] = 0.f;
}

// ---------------- CSR build (split kernels: full occupancy per phase) --------
// R6 lesson: grid-barrier fusion caps occupancy (205 us). R8 lesson: wide
// single-cell tickets serialize ~150-250ns/atomic across XCDs. Split
// dispatches at ~4us each are the cheap option.
__global__ void deg_count(const int* __restrict__ ei, int* __restrict__ deg, int E) {
  int e = blockIdx.x * 256 + threadIdx.x;
  if (e < E) atomicAdd(&deg[ei[E + e]], 1);
}

__global__ __launch_bounds__(256) void scan_sum(const int* __restrict__ deg,
                                                int* __restrict__ partials, int N) {
  __shared__ int red[256];
  int b = blockIdx.x, t = threadIdx.x;
  int base = b * SCAN_CHUNK + t * 2;
  int s = 0;
  if (base + 1 < N) { int2 v = *reinterpret_cast<const int2*>(deg + base); s = v.x + v.y; }
  else if (base < N) s = deg[base];
  red[t] = s;
  __syncthreads();
  for (int off = 128; off; off >>= 1) {
    if (t < off) red[t] += red[t + off];
    __syncthreads();
  }
  if (t == 0) partials[b] = red[0];
}

__global__ __launch_bounds__(256) void scan_apply(const int* __restrict__ deg,
                                                  const int* __restrict__ partials,
                                                  int* __restrict__ rowptr,
                                                  int* __restrict__ cursor, int N, int E) {
  __shared__ int s[256];
  __shared__ int prefSh;
  int b = blockIdx.x, t = threadIdx.x;

  s[t] = (t < b) ? partials[t] : 0;    // b <= 97 < 256
  __syncthreads();
  for (int off = 128; off; off >>= 1) {
    if (t < off) s[t] += s[t + off];
    __syncthreads();
  }
  if (t == 0) prefSh = s[0];
  __syncthreads();
  int pref = prefSh;
  __syncthreads();

  int base = b * SCAN_CHUNK + t * 2;
  int d0 = 0, d1 = 0;
  if (base + 1 < N) { int2 v = *reinterpret_cast<const int2*>(deg + base); d0 = v.x; d1 = v.y; }
  else if (base < N) d0 = deg[base];
  int local = d0 + d1;
  s[t] = local;
  __syncthreads();
  for (int off = 1; off < 256; off <<= 1) {
    int o = (t >= off) ? s[t - off] : 0;
    __syncthreads();
    s[t] += o;
    __syncthreads();
  }
  int offp = pref + s[t] - local;
  if (base < N)     { rowptr[base] = offp;          cursor[base] = offp; }
  if (base + 1 < N) { rowptr[base + 1] = offp + d0; cursor[base + 1] = offp + d0; }
  if (b == 0 && t == 0) rowptr[N] = E;
}

__global__ void csr_scatter(const int* __restrict__ ei, int* __restrict__ cursor,
                            int* __restrict__ adj, int E) {
  int e = blockIdx.x * 256 + threadIdx.x;
  if (e < E) {
    int dst = ei[E + e];
    int pos = atomicAdd(&cursor[dst], 1);
    adj[pos] = ei[e];
  }
}

// Canonical stable ascending rank-sort of 16 rows (16 lanes/row, cap 32 >>
// max degree ~28 for Poisson(8)); identical result to insertion sort.
// Runs as extra blocks of the L0 gemm dispatch: sort blocks touch only adj
// (gemm blocks touch Q/KV/H) — disjoint data, no inter-block ordering needed,
// and node_attn consumes adj only in the NEXT dispatch. Result is
// timing-independent -> deterministic.
DEV void adj_sort_body(const int* __restrict__ rowptr, int* __restrict__ adj,
                       int nodeBase, int N) {
  __shared__ int sbuf[16 * 32];
  int t = threadIdx.x;
  int g = t >> 4, l = t & 15;
  int n = nodeBase + g;
  bool valid = n < N;
  int p0 = 0, d = 0;
  if (valid) { p0 = rowptr[n]; d = rowptr[n + 1] - p0; }
  if (__builtin_expect(d > 32, 0)) {
    if (l == 0) {                      // rare fallback: serial insertion sort
      for (int i = p0 + 1; i < p0 + d; ++i) {
        int v = adj[i]; int j = i - 1;
        while (j >= p0 && adj[j] > v) { adj[j + 1] = adj[j]; --j; }
        adj[j + 1] = v;
      }
    }
    d = 0;
  }
  int a0 = (l < d) ? adj[p0 + l] : 0x7fffffff;
  int a1 = (16 + l < d) ? adj[p0 + 16 + l] : 0x7fffffff;
  int r0 = 0, r1 = 0;
#pragma unroll
  for (int i = 0; i < 16; ++i) {
    int v0 = __shfl(a0, i, 16);
    int v1 = __shfl(a1, i, 16);
    r0 += (v0 < a0) || (v0 == a0 && i < l);
    r0 += (v1 < a0);
    r1 += (v0 <= a1);
    r1 += (v1 < a1) || (v1 == a1 && i < l);
  }
  if (l < d)      sbuf[g * 32 + r0] = a0;
  if (16 + l < d) sbuf[g * 32 + r1] = a1;
  __syncthreads();
  if (l < d)      adj[p0 + l]      = sbuf[g * 32 + l];
  if (16 + l < d) adj[p0 + 16 + l] = sbuf[g * 32 + 16 + l];
}

// ---------------- fused 4-projection GEMM: {Q,K,V,H} = BN(X) @ W_p + b_p -----
// L0 additionally carries adj_sort in blocks >= nbGemm (independent work,
// no sync — NOT the R8 ticket pattern, which is what regressed).
struct GemmOut { _Float16* Y[4]; const float* bias[4]; int ldY[4]; };

#define LDP 136   // padded LDS row stride (bf16/fp16 elems)

__global__ __launch_bounds__(256) void gemm_proj(
    const float* __restrict__ Xf,
    const _Float16* __restrict__ Hin,
    const float* __restrict__ scale, const float* __restrict__ shift,
    const unsigned short* __restrict__ WB4,   // fragment-ordered, 4 mats x 16384
    GemmOut go, int useBN, int N, int nbGemm,
    const int* __restrict__ rowptr, int* __restrict__ adj)
{
  __shared__ __align__(16) unsigned short xs[64 * LDP];

  if ((int)blockIdx.x >= nbGemm) {            // L0 only: fused adjacency sort
    adj_sort_body(rowptr, adj, ((int)blockIdx.x - nbGemm) * 16, N);
    return;
  }

  const int t = threadIdx.x;
  const int rowBase = blockIdx.x * 64;
  const int igc = (t & 15) * 8;

  if (useBN) {
    float4 sc0 = *reinterpret_cast<const float4*>(scale + igc);
    float4 sc1 = *reinterpret_cast<const float4*>(scale + igc + 4);
    float4 sh0 = *reinterpret_cast<const float4*>(shift + igc);
    float4 sh1 = *reinterpret_cast<const float4*>(shift + igc + 4);
#pragma unroll
    for (int j = 0; j < 4; ++j) {
      int v = t + 256 * j;
      int r = v >> 4;
      int grow = rowBase + r;
      ushort4 o0 = make_ushort4(0, 0, 0, 0), o1 = make_ushort4(0, 0, 0, 0);
      if (grow < N) {
        f16x8 hv = *reinterpret_cast<const f16x8*>(Hin + (size_t)grow * 128 + igc);
        o0.x = f2bf(fmaxf((float)hv[0] * sc0.x + sh0.x, 0.f));
        o0.y = f2bf(fmaxf((float)hv[1] * sc0.y + sh0.y, 0.f));
        o0.z = f2bf(fmaxf((float)hv[2] * sc0.z + sh0.z, 0.f));
        o0.w = f2bf(fmaxf((float)hv[3] * sc0.w + sh0.w, 0.f));
        o1.x = f2bf(fmaxf((float)hv[4] * sc1.x + sh1.x, 0.f));
        o1.y = f2bf(fmaxf((float)hv[5] * sc1.y + sh1.y, 0.f));
        o1.z = f2bf(fmaxf((float)hv[6] * sc1.z + sh1.z, 0.f));
        o1.w = f2bf(fmaxf((float)hv[7] * sc1.w + sh1.w, 0.f));
      }
      *reinterpret_cast<ushort4*>(&xs[r * LDP + igc]) = o0;
      *reinterpret_cast<ushort4*>(&xs[r * LDP + igc + 4]) = o1;
    }
  } else {
#pragma unroll
    for (int j = 0; j < 4; ++j) {
      int v = t + 256 * j;
      int r = v >> 4;
      int grow = rowBase + r;
      ushort4 o0 = make_ushort4(0, 0, 0, 0), o1 = make_ushort4(0, 0, 0, 0);
      if (grow < N) {
        float4 a = *reinterpret_cast<const float4*>(Xf + (size_t)grow * 128 + igc);
        float4 b = *reinterpret_cast<const float4*>(Xf + (size_t)grow * 128 + igc + 4);
        o0.x = f2bf(a.x); o0.y = f2bf(a.y); o0.z = f2bf(a.z); o0.w = f2bf(a.w);
        o1.x = f2bf(b.x); o1.y = f2bf(b.y); o1.z = f2bf(b.z); o1.w = f2bf(b.w);
      }
      *reinterpret_cast<ushort4*>(&xs[r * LDP + igc]) = o0;
      *reinterpret_cast<ushort4*>(&xs[r * LDP + igc + 4]) = o1;
    }
  }
  __syncthreads();

  const int wave = t >> 6;
  const int lane = t & 63;
  const int ln16 = lane & 15;
  const int quad = lane >> 4;
  const int r0 = wave * 16;

  bf16x8 afrag[4];
#pragma unroll
  for (int kk = 0; kk < 4; ++kk)
    afrag[kk] = *reinterpret_cast<const bf16x8*>(&xs[(r0 + ln16) * LDP + kk * 32 + quad * 8]);
  __syncthreads();   // xs becomes per-wave epilogue scratch below

  for (int proj = 0; proj < 4; ++proj) {
    const unsigned short* __restrict__ WB = WB4 + proj * 16384;
    const float* __restrict__ bias = go.bias[proj];

    f32x4 acc[8] = {};
#pragma unroll
    for (int kk = 0; kk < 4; ++kk) {
#pragma unroll
      for (int ct = 0; ct < 8; ++ct) {
        bf16x8 b = *reinterpret_cast<const bf16x8*>(WB + ((kk * 8 + ct) * 64 + lane) * 8);
        acc[ct] = __builtin_amdgcn_mfma_f32_16x16x32_bf16(afrag[kk], b, acc[ct], 0, 0, 0);
      }
    }

    _Float16* __restrict__ Yh = go.Y[proj];
    const int ldY = go.ldY[proj];
#pragma unroll
    for (int ct = 0; ct < 8; ++ct) {
      int col = ct * 16 + ln16;
      float bv = bias[col];
#pragma unroll
      for (int reg = 0; reg < 4; ++reg) {
        _Float16 hv = (_Float16)(acc[ct][reg] + bv);
        xs[(r0 + quad * 4 + reg) * LDP + col] = __builtin_bit_cast(unsigned short, hv);
      }
    }
#pragma unroll
    for (int pass = 0; pass < 4; ++pass) {
      int rl = (lane >> 4) + pass * 4;       // 0..15
      int grow = rowBase + r0 + rl;
      f16x8 v = *reinterpret_cast<const f16x8*>(&xs[(r0 + rl) * LDP + ln16 * 8]);
      if (grow < N)
        *reinterpret_cast<f16x8*>(&Yh[(size_t)grow * ldY + ln16 * 8]) = v;
    }
  }
}

// ---------------- fused per-node attention + BN partial stats ----------------
// 16 lanes per node, 16 nodes per 256-thread block. KV interleaved per node.
// No device-scope fences/tickets here (R5/R8 lessons). H row hoisted.
__global__ __launch_bounds__(256) void node_attn(
    const int* __restrict__ rowptr, const int* __restrict__ adj,
    const _Float16* __restrict__ Q, const _Float16* __restrict__ KV,
    _Float16* __restrict__ H, float* __restrict__ Pbuf, int N)
{
  __shared__ float lsum[16][132];
  __shared__ float lsq[16][132];
  int t = threadIdx.x;
  int w = t >> 4, lane = t & 15;
  int n = blockIdx.x * 16 + w;
  bool valid = n < N;
  int nn = valid ? n : 0;
  int p0 = 0, p1 = 0;
  if (valid) { p0 = rowptr[n]; p1 = rowptr[n + 1]; }
  int d = p1 - p0;

  f16x8 qv = *reinterpret_cast<const f16x8*>(Q + (size_t)nn * 128 + lane * 8);
  f16x8 hh = *reinterpret_cast<const f16x8*>(H + (size_t)nn * 128 + lane * 8);
  f16x2 q0 = {qv[0], qv[1]}, q1 = {qv[2], qv[3]}, q2 = {qv[4], qv[5]}, q3 = {qv[6], qv[7]};

  const float rsqd = 0.08838834764831845f;
  float m = -INFINITY, s = 0.f;
  float acc[8] = {};

#define EDGE1(SRC) do {                                                        \
    const _Float16* bp_ = KV + (size_t)(SRC) * 256 + lane * 8;                 \
    f16x8 ke_ = *reinterpret_cast<const f16x8*>(bp_);                          \
    f16x8 ve_ = *reinterpret_cast<const f16x8*>(bp_ + 128);                    \
    float dd_ = fdot2acc(q0, (f16x2){ke_[0], ke_[1]},                          \
                fdot2acc(q1, (f16x2){ke_[2], ke_[3]},                          \
                fdot2acc(q2, (f16x2){ke_[4], ke_[5]},                          \
                fdot2acc(q3, (f16x2){ke_[6], ke_[7]}, 0.f))));                 \
    for (int off_ = 8; off_; off_ >>= 1) dd_ += __shfl_xor(dd_, off_, 16);     \
    float ll_ = dd_ * rsqd;                                                    \
    float mn_ = fmaxf(m, ll_);                                                 \
    float sc_ = __expf(m - mn_);                                               \
    float w0_ = __expf(ll_ - mn_);                                             \
    for (int i_ = 0; i_ < 8; ++i_) acc[i_] = acc[i_] * sc_ + w0_ * (float)ve_[i_]; \
    s = s * sc_ + w0_;                                                         \
    m = mn_;                                                                   \
  } while (0)

  if (__builtin_expect(d <= 32, 1)) {
    int aLo = (lane < d) ? adj[p0 + lane] : 0;
    int aHi = (16 + lane < d) ? adj[p0 + 16 + lane] : 0;
    int e = 0;
    for (; e + 1 < d; e += 2) {
      int s0 = __shfl((e     < 16) ? aLo : aHi, (e    ) & 15, 16);
      int s1 = __shfl((e + 1 < 16) ? aLo : aHi, (e + 1) & 15, 16);
      const _Float16* b0 = KV + (size_t)s0 * 256 + lane * 8;
      const _Float16* b1 = KV + (size_t)s1 * 256 + lane * 8;
      f16x8 k0 = *reinterpret_cast<const f16x8*>(b0);
      f16x8 k1 = *reinterpret_cast<const f16x8*>(b1);
      f16x8 v0 = *reinterpret_cast<const f16x8*>(b0 + 128);
      f16x8 v1 = *reinterpret_cast<const f16x8*>(b1 + 128);
      float d0 = fdot2acc(q0, (f16x2){k0[0], k0[1]},
                 fdot2acc(q1, (f16x2){k0[2], k0[3]},
                 fdot2acc(q2, (f16x2){k0[4], k0[5]},
                 fdot2acc(q3, (f16x2){k0[6], k0[7]}, 0.f))));
      float d1 = fdot2acc(q0, (f16x2){k1[0], k1[1]},
                 fdot2acc(q1, (f16x2){k1[2], k1[3]},
                 fdot2acc(q2, (f16x2){k1[4], k1[5]},
                 fdot2acc(q3, (f16x2){k1[6], k1[7]}, 0.f))));
#pragma unroll
      for (int off = 8; off; off >>= 1) {
        d0 += __shfl_xor(d0, off, 16);
        d1 += __shfl_xor(d1, off, 16);
      }
      float l0 = d0 * rsqd;
      float l1 = d1 * rsqd;
      float mn = fmaxf(m, fmaxf(l0, l1));
      float sc = __expf(m - mn);
      float w0 = __expf(l0 - mn);
      float w1 = __expf(l1 - mn);
#pragma unroll
      for (int i = 0; i < 8; ++i)
        acc[i] = acc[i] * sc + w0 * (float)v0[i] + w1 * (float)v1[i];
      s = s * sc + w0 + w1;
      m = mn;
    }
    if (e < d) {
      int sE = __shfl((e < 16) ? aLo : aHi, e & 15, 16);
      EDGE1(sE);
    }
  } else {
    for (int p = p0; p < p1; ++p) { int sE = adj[p]; EDGE1(sE); }
  }
#undef EDGE1

  float h[8];
#pragma unroll
  for (int i = 0; i < 8; ++i) h[i] = 0.f;
  if (valid) {
    float inv = 1.0f / (s + 1e-16f);
    f16x8 ho;
#pragma unroll
    for (int i = 0; i < 8; ++i) {
      h[i] = (float)hh[i] + acc[i] * inv;
      ho[i] = (_Float16)h[i];
    }
    *reinterpret_cast<f16x8*>(H + (size_t)n * 128 + lane * 8) = ho;
  }

  // BN partial stats
#pragma unroll
  for (int i = 0; i < 8; i += 4) {
    float4 hv = make_float4(h[i], h[i + 1], h[i + 2], h[i + 3]);
    float4 h2 = make_float4(hv.x * hv.x, hv.y * hv.y, hv.z * hv.z, hv.w * hv.w);
    *reinterpret_cast<float4*>(&lsum[w][lane * 8 + i]) = hv;
    *reinterpret_cast<float4*>(&lsq[w][lane * 8 + i]) = h2;
  }
  __syncthreads();

  int f = t & 127;
  float a = 0.f;
  if (t < 128) {
#pragma unroll
    for (int n16 = 0; n16 < 16; ++n16) a += lsum[n16][f];
  } else {
#pragma unroll
    for (int n16 = 0; n16 < 16; ++n16) a += lsq[n16][f];
  }
  Pbuf[(size_t)blockIdx.x * 256 + t] = a;
}

// ---------------- fused BN reduce (ticket: last of 64 blocks finishes) -------
// 64 tickets on one cell ≈ 10us worst case — acceptable (R8 rule: ≲64 only).
__global__ __launch_bounds__(256) void bn_fused(
    const float* __restrict__ Pbuf, float* __restrict__ bnpart,
    const float* __restrict__ gamma, const float* __restrict__ beta,
    float* __restrict__ scale, float* __restrict__ shift,
    int* __restrict__ ticket, int N)
{
  __shared__ float red[256];
  __shared__ int amLast;
  int t = threadIdx.x;
  {
    float s0 = 0.f, s1 = 0.f, s2 = 0.f, s3 = 0.f;
    int r = blockIdx.x;
    for (; r + 192 < ATTN_BLOCKS; r += 256) {
      s0 += Pbuf[(size_t)(r      ) * 256 + t];
      s1 += Pbuf[(size_t)(r +  64) * 256 + t];
      s2 += Pbuf[(size_t)(r + 128) * 256 + t];
      s3 += Pbuf[(size_t)(r + 192) * 256 + t];
    }
    for (; r < ATTN_BLOCKS; r += 64) s0 += Pbuf[(size_t)r * 256 + t];
    bnpart[blockIdx.x * 256 + t] = s0 + s1 + s2 + s3;
  }
  __threadfence();                       // release partials (device scope)
  if (t == 0) amLast = (atomicAdd(ticket, 1) == 63);
  __syncthreads();
  if (!amLast) return;
  __threadfence();                       // acquire all blocks' partials

  float s0 = 0.f, s1 = 0.f, s2 = 0.f, s3 = 0.f;
#pragma unroll
  for (int r = 0; r < 64; r += 4) {
    s0 += bnpart[(r + 0) * 256 + t];
    s1 += bnpart[(r + 1) * 256 + t];
    s2 += bnpart[(r + 2) * 256 + t];
    s3 += bnpart[(r + 3) * 256 + t];
  }
  red[t] = s0 + s1 + s2 + s3;
  __syncthreads();
  if (t < 128) {
    float mean = red[t] / (float)N;
    float var = red[t + 128] / (float)N - mean * mean;
    var = fmaxf(var, 0.f);
    float sc = gamma[t] * rsqrtf(var + 1e-5f);
    scale[t] = sc;
    shift[t] = beta[t] - mean * sc;
  }
}

// ---------------- deterministic parallel pooling ----------------------------
__global__ __launch_bounds__(256) void pool_partial(
    const _Float16* __restrict__ H, const float* __restrict__ scale,
    const float* __restrict__ shift, const int* __restrict__ batch,
    float* __restrict__ partial, int N)
{
  int f = threadIdx.x & 127, parity = threadIdx.x >> 7;
  int base = blockIdx.x * 64;
  int lim = min(base + 64, N);
  float sc = scale[f], sh = shift[f];
  int slot = ((blockIdx.x & 7) << 1) | parity;
  int curg = -1; float s = 0.f;
  for (int row = base + parity; row < lim; row += 2) {
    int g = batch[row];
    if (g != curg) {
      if (curg >= 0) partial[(size_t)((curg << 4) | slot) * 128 + f] = s;
      curg = g; s = 0.f;
    }
    s += fmaxf((float)H[(size_t)row * 128 + f] * sc + sh, 0.f);
  }
  if (curg >= 0) partial[(size_t)((curg << 4) | slot) * 128 + f] = s;
}

// ---------------- final linear (fused slot-reduce + classifier) --------------
__global__ __launch_bounds__(128) void final_linear(
    const float* __restrict__ partial, const int* __restrict__ batch,
    const float* __restrict__ Wlin, const float* __restrict__ blin,
    float* __restrict__ out, int N)
{
  __shared__ float pf[128];
  int g = blockIdx.x;
  int t = threadIdx.x;
  float s = 0.f;
#pragma unroll
  for (int sl = 0; sl < PSLOTS; ++sl)
    s += partial[(size_t)((g << 4) | sl) * 128 + t];
  pf[t] = s;
  __syncthreads();
  int lo = 0, hi = N;
  while (lo < hi) { int mid = (lo + hi) >> 1; if (batch[mid] < g) lo = mid + 1; else hi = mid; }
  int start = lo;
  hi = N;
  while (lo < hi) { int mid = (lo + hi) >> 1; if (batch[mid] < g + 1) lo = mid + 1; else hi = mid; }
  float inv = 1.0f / fmaxf((float)(lo - start), 1.f);
  if (t < 20) {
    float acc = 0.f;
#pragma unroll 4
    for (int i = 0; i < 128; ++i)
      acc += pf[i] * Wlin[i * 20 + t];
    out[g * 20 + t] = acc * inv + blin[t];
  }
}

// =============================================================================
extern "C" void kernel_launch(void* const* d_in, const int* in_sizes, int n_in,
                              void* d_out, int out_size, void* d_ws, size_t ws_size,
                              hipStream_t stream)
{
  const int N = N_NODES, E = N_EDGES, G = N_GRAPHS;

  const float* x = (const float*)d_in[0];
  const int* ei = (const int*)d_in[1];
  const int* batch = (const int*)d_in[2];
  const float* Wlin = (const float*)d_in[33];
  const float* blin = (const float*)d_in[34];

  char* ws = (char*)d_ws;
  size_t off = 0;
  auto alloc = [&](size_t bytes) -> void* {
    void* p = ws + off;
    off = (off + bytes + 255) & ~(size_t)255;
    return p;
  };
  unsigned short* WB = (unsigned short*)alloc(12 * 16384 * sizeof(unsigned short));
  _Float16* Qh  = (_Float16*)alloc((size_t)N * 128 * 2);
  _Float16* KVh = (_Float16*)alloc((size_t)N * 256 * 2);
  _Float16* Hh  = (_Float16*)alloc((size_t)N * 128 * 2);
  int* rowptr   = (int*)alloc((size_t)(N + 1) * 4);
  int* cursor   = (int*)alloc((size_t)N * 4);
  int* adj      = (int*)alloc((size_t)E * 4);
  int* partials = (int*)alloc((size_t)N_CHUNKS * 4);
  float* Pbuf   = (float*)alloc((size_t)ATTN_BLOCKS * 256 * 4);
  float* bnpart = (float*)alloc((size_t)64 * 256 * 4);
  float* scale  = (float*)alloc(128 * 4);
  float* shift  = (float*)alloc(128 * 4);
  int* deg      = (int*)alloc((size_t)N * 4);
  int* ctrl     = (int*)alloc(64 * 4);      // tickets (zeroed in repack_zero)
  float* ppool  = (float*)alloc((size_t)G * PSLOTS * 128 * 4);

  WPtrs wp;
  for (int L = 0; L < 3; ++L) {
    wp.w[L * 4 + 0] = (const float*)d_in[3 + L * 10 + 0];  // Wq
    wp.w[L * 4 + 1] = (const float*)d_in[3 + L * 10 + 2];  // Wk
    wp.w[L * 4 + 2] = (const float*)d_in[3 + L * 10 + 4];  // Wv
    wp.w[L * 4 + 3] = (const float*)d_in[3 + L * 10 + 6];  // Ws
  }

  repack_zero<<<768, 256, 0, stream>>>(wp, WB, deg, ctrl, ppool, N);
  deg_count<<<(E + 255) / 256, 256, 0, stream>>>(ei, deg, E);
  scan_sum<<<N_CHUNKS, 256, 0, stream>>>(deg, partials, N);
  scan_apply<<<N_CHUNKS, 256, 0, stream>>>(deg, partials, rowptr, cursor, N, E);
  csr_scatter<<<(E + 255) / 256, 256, 0, stream>>>(ei, cursor, adj, E);

  for (int L = 0; L < 3; ++L) {
    GemmOut go;
    go.Y[0] = Qh;        go.ldY[0] = 128;
    go.Y[1] = KVh;       go.ldY[1] = 256;   // K at +0
    go.Y[2] = KVh + 128; go.ldY[2] = 256;   // V at +128
    go.Y[3] = Hh;        go.ldY[3] = 128;
    go.bias[0] = (const float*)d_in[3 + L * 10 + 1];
    go.bias[1] = (const float*)d_in[3 + L * 10 + 3];
    go.bias[2] = (const float*)d_in[3 + L * 10 + 5];
    go.bias[3] = (const float*)d_in[3 + L * 10 + 7];

    if (L == 0) {
      // one dispatch: 782 gemm blocks + 3125 adj_sort blocks (disjoint data)
      gemm_proj<<<NB_GEMM + ATTN_BLOCKS, 256, 0, stream>>>(
          x, Hh, scale, shift, WB, go, 0, N, NB_GEMM, rowptr, adj);
    } else {
      gemm_proj<<<NB_GEMM, 256, 0, stream>>>(
          x, Hh, scale, shift, WB + L * 4 * 16384, go, 1, N, NB_GEMM,
          nullptr, nullptr);
    }

    node_attn<<<ATTN_BLOCKS, 256, 0, stream>>>(rowptr, adj, Qh, KVh, Hh, Pbuf, N);

    bn_fused<<<64, 256, 0, stream>>>(Pbuf, bnpart,
        (const float*)d_in[3 + L * 10 + 8],
        (const float*)d_in[3 + L * 10 + 9],
        scale, shift, ctrl + L, N);

    if (L == 2) {
      pool_partial<<<POOL_CHUNKS, 256, 0, stream>>>(Hh, scale, shift, batch, ppool, N);
      final_linear<<<G, 128, 0, stream>>>(ppool, batch, Wlin, blin, (float*)d_out, N);
    }
  }
}